// Round 6
// baseline (163.698 us; speedup 1.0000x reference)
//
#include <hip/hip_runtime.h>

// EdgeAttention round 14: single-barrier 3-buffer pipelines + fused softmax.
//  - pd & ps K-loops: triple-buffered DMA. D(k+2) is issued right AFTER the
//    iter-k start barrier into buf (k+2)%3 (its last reader was iter k-1,
//    published by this barrier) -> the r11/r13 second barrier + lgkmcnt(0)
//    per iter is gone. vmcnt(6) counting unchanged (6 DMA instr/wave/iter,
//    issue-after-wait keeps D(k+1)'s 6 in flight).
//  - softmax4 fused into pd: __threadfence + atomicAdd counter; 200th block
//    computes the softmax (counter zeroed by pack_w, which runs first).
//  - pd LDS: 3x(16K W + 32K F) = 147456 B dynamic; epilogue S aliases as r13.
//  - ps LDS: 3x(16K W + 8K F) = 72 KB static.
// pack_w / epilogue bodies r13-verbatim.

#define CCH 256

typedef __attribute__((ext_vector_type(8))) short short8;
typedef __attribute__((ext_vector_type(4))) short short4_;
typedef __attribute__((ext_vector_type(4))) float float4_;

__device__ inline short f2bf(float x) {
    union { float f; unsigned u; } c; c.f = x;
    unsigned u = c.u + 0x7FFFu + ((c.u >> 16) & 1u);
    return (short)(u >> 16);
}
__device__ inline float bf2f(short b) {
    union { unsigned u; float f; } c; c.u = ((unsigned)(unsigned short)b) << 16;
    return c.f;
}

__device__ inline void dma16(const void* g, void* l) {
    __builtin_amdgcn_global_load_lds(
        (const __attribute__((address_space(1))) void*)g,
        (__attribute__((address_space(3))) void*)l, 16, 0, 0);
}

// ---------- pack_w: w0..w3 fp32 -> bf16 fragment-linear; zeroes pd's counter ----
__global__ __launch_bounds__(256) void pack_w(
    const float* __restrict__ w0, const float* __restrict__ w1,
    const float* __restrict__ w2, const float* __restrict__ w3,
    short* __restrict__ wp, unsigned* __restrict__ counter)
{
    if (blockIdx.x == 0 && threadIdx.x == 0) *counter = 0u;
    int id = blockIdx.x * 256 + threadIdx.x;     // 0..32767 short8s
    int mtx = id >> 13;
    const float* w = (mtx == 0) ? w0 : (mtx == 1) ? w1 : (mtx == 2) ? w2 : w3;
    int rest = id & 8191;
    int ks = rest >> 10;
    int r2 = rest & 1023;
    int mt = r2 >> 6;
    int fl = r2 & 63;
    int ln = fl & 15, qd = fl >> 4;
    const float* src = w + (size_t)(mt * 16 + ln) * CCH + ks * 32 + qd * 8;
    short8 v;
#pragma unroll
    for (int j = 0; j < 8; ++j) v[j] = f2bf(src[j]);
    *(short8*)(wp + (size_t)id * 8) = v;
}

// ---------- proj_small v3: 3-buffer single-barrier DMA pipeline ----------
// 272 blocks, 4 waves. Block -> (scale, b, 64-px tile). Wave w owns px w*16+ln.
__global__ __launch_bounds__(256) void proj_small(
    const float* __restrict__ f1, const float* __restrict__ f2,
    const float* __restrict__ f3, const short* __restrict__ wp,
    const float* __restrict__ b1, const float* __restrict__ b2,
    const float* __restrict__ b3,
    short* __restrict__ u1, short* __restrict__ u2, short* __restrict__ u3)
{
    __shared__ __align__(16) short Wt0[16 * 512];   // 16 KB each
    __shared__ __align__(16) short Wt1[16 * 512];
    __shared__ __align__(16) short Wt2[16 * 512];
    __shared__ __align__(16) float Ft0[32 * 64];    //  8 KB each
    __shared__ __align__(16) float Ft1[32 * 64];
    __shared__ __align__(16) float Ft2[32 * 64];

    const int blk = blockIdx.x;
    const int t = threadIdx.x;

    int b, tile, L, sidx;
    const float* F; const float* bias; short* U;
    if (blk < 200)      { int r = blk;       b = r / 25; tile = r % 25; L = 1600; F = f1; bias = b1; U = u1; sidx = 1; }
    else if (blk < 256) { int r = blk - 200; b = r / 7;  tile = r % 7;  L = 400;  F = f2; bias = b2; U = u2; sidx = 2; }
    else                { int r = blk - 256; b = r / 2;  tile = r % 2;  L = 100;  F = f3; bias = b3; U = u3; sidx = 3; }

    const int lane = t & 63;
    const int wav  = t >> 6;           // 0..3
    const int ln   = lane & 15;
    const int quad = lane >> 4;
    const int pixbase = tile * 64;
    const float* Fb = F + (size_t)b * CCH * L;
    const short* wps = wp + (size_t)sidx * 65536;

    int gp = pixbase + (lane & 15) * 4;
    if (gp > L - 4) gp = L - 4;
    const int chq = lane >> 4;

    auto dmaW = [&](int ks, int buf) {             // 4 instr/wave (16 KB total)
        short* Wb = (buf == 0) ? Wt0 : (buf == 1) ? Wt1 : Wt2;
#pragma unroll
        for (int m = 0; m < 4; ++m) {
            const int k = wav * 4 + m;                      // mt 0..15
            dma16(wps + (size_t)ks * 8192 + k * 512 + lane * 8, Wb + k * 512);
        }
    };
    auto dmaF = [&](int ks, int buf) {             // 2 instr/wave (8 KB total)
        float* Fl = (buf == 0) ? Ft0 : (buf == 1) ? Ft1 : Ft2;
#pragma unroll
        for (int m = 0; m < 2; ++m) {
            const int k4 = wav * 2 + m;                     // 4-ch group 0..7
            const int ch = k4 * 4 + chq;
            dma16(Fb + (size_t)(ks * 32 + ch) * L + gp, Fl + k4 * 256);
        }
    };

    float4_ acc[16];
#pragma unroll
    for (int i = 0; i < 16; ++i) acc[i] = (float4_){0.f, 0.f, 0.f, 0.f};

    const int fpx = wav * 16 + ln;     // this lane's pixel 0..63

    dmaW(0, 0); dmaF(0, 0);
    dmaW(1, 1); dmaF(1, 1);
#pragma unroll
    for (int ks = 0; ks < 8; ++ks) {
        if (ks < 7) asm volatile("s_waitcnt vmcnt(6)" ::: "memory");
        else        asm volatile("s_waitcnt vmcnt(0)" ::: "memory");
        __builtin_amdgcn_s_barrier();
        if (ks < 6) { dmaW(ks + 2, (ks + 2) % 3); dmaF(ks + 2, (ks + 2) % 3); }

        const short* Wl = (ks % 3 == 0) ? Wt0 : (ks % 3 == 1) ? Wt1 : Wt2;
        const float* Fl = (ks % 3 == 0) ? Ft0 : (ks % 3 == 1) ? Ft1 : Ft2;
        short8 bfrag;
#pragma unroll
        for (int j = 0; j < 8; ++j)
            bfrag[j] = f2bf(Fl[(quad * 8 + j) * 64 + fpx]);
#pragma unroll
        for (int mt = 0; mt < 16; ++mt) {
            short8 afrag = *(const short8*)(Wl + mt * 512 + lane * 8);
            acc[mt] = __builtin_amdgcn_mfma_f32_16x16x32_bf16(afrag, bfrag, acc[mt], 0, 0, 0);
        }
    }

    float ss = 0.f;
#pragma unroll
    for (int mt = 0; mt < 16; ++mt) {
        float4_ bv = *(const float4_*)(bias + mt * 16 + quad * 4);
#pragma unroll
        for (int r = 0; r < 4; ++r) { float v = acc[mt][r] + bv[r]; acc[mt][r] = v; ss += v * v; }
    }
    ss += __shfl_xor(ss, 16);
    ss += __shfl_xor(ss, 32);
    const float inv = 1.f / sqrtf(fmaxf(ss, 1e-24f));

    const int gpixw = pixbase + fpx;
    if (gpixw < L) {
        short* dst = U + ((size_t)b * L + gpixw) * CCH;
#pragma unroll
        for (int mt = 0; mt < 16; ++mt) {
            short4_ v;
#pragma unroll
            for (int r = 0; r < 4; ++r) v[r] = f2bf(acc[mt][r] * inv);
            *(short4_*)(dst + mt * 16 + quad * 4) = v;
        }
    }
}

// ---------- proj0_dots v6: 3-buffer single-barrier pipeline + fused softmax ------
#define SPITCH 264
__global__ __launch_bounds__(512) void proj0_dots(
    const float* __restrict__ F, const short* __restrict__ wp,
    const float* __restrict__ bias,
    const short* __restrict__ u1, const short* __restrict__ u2,
    const short* __restrict__ u3,
    float* __restrict__ partial, unsigned* __restrict__ counter,
    float* __restrict__ out)
{
    extern __shared__ __align__(16) char smem[];  // 147456 B dynamic
    short* Wb0 = (short*)smem;                    // 16 KB W bufs
    short* Wb1 = (short*)(smem + 16384);
    short* Wb2 = (short*)(smem + 32768);
    float* Fb0 = (float*)(smem + 49152);          // 32 KB F bufs
    float* Fb1 = (float*)(smem + 81920);
    float* Fb2 = (float*)(smem + 114688);         // ends 147456
    short* S1 = (short*)smem;                     // 64 px * 264 * 2 = 33792 B
    short* S2 = (short*)(smem + 33792);           // 16 px           =  8448 B
    short* S3 = (short*)(smem + 42240);           //  4 px           =  2112 B
    float* redF = (float*)(smem + 44352);         // [8][3]
    float* redC = (float*)(smem + 44448);         // [9]
    int*   lastF = (int*)(smem + 44544);          // last-block flag

    const int c  = blockIdx.x;         // 0..24
    const int b  = blockIdx.y;
    const int R  = c / 5, C = c - R * 5;
    const int t  = threadIdx.x;
    const int lane = t & 63;
    const int wav  = t >> 6;           // 0..7
    const int ln   = lane & 15;
    const int quad = lane >> 4;
    const float* Fbase = F + (size_t)b * CCH * 6400;

    auto dmaW = [&](int ks, int buf) {             // 2 instr/wave (16 KB total)
        short* Wb = (buf == 0) ? Wb0 : (buf == 1) ? Wb1 : Wb2;
#pragma unroll
        for (int m = 0; m < 2; ++m) {
            const int k = wav * 2 + m;                      // 0..15
            dma16(wp + (size_t)ks * 8192 + k * 512 + lane * 8, Wb + k * 512);
        }
    };
    auto dmaF = [&](int ks, int buf) {             // 4 instr/wave (32 KB total)
        float* Fl = (buf == 0) ? Fb0 : (buf == 1) ? Fb1 : Fb2;
        const int gpx = (16 * R + (lane >> 2)) * 80 + 16 * C + (lane & 3) * 4;
#pragma unroll
        for (int m = 0; m < 4; ++m) {
            const int k = wav * 4 + m;                      // channel 0..31
            dma16(Fbase + (size_t)(ks * 32 + k) * 6400 + gpx, Fl + k * 256);
        }
    };

    float4_ accA[16], accB[16];
#pragma unroll
    for (int i = 0; i < 16; ++i) {
        accA[i] = (float4_){0.f, 0.f, 0.f, 0.f};
        accB[i] = (float4_){0.f, 0.f, 0.f, 0.f};
    }

    const int pxA = wav * 32 + ln;     // fine row 2w, col ln
    const int pxB = pxA + 16;          // fine row 2w+1

    dmaW(0, 0); dmaF(0, 0);
    dmaW(1, 1); dmaF(1, 1);
#pragma unroll
    for (int ks = 0; ks < 8; ++ks) {
        if (ks < 7) asm volatile("s_waitcnt vmcnt(6)" ::: "memory");
        else        asm volatile("s_waitcnt vmcnt(0)" ::: "memory");
        __builtin_amdgcn_s_barrier();
        if (ks < 6) { dmaW(ks + 2, (ks + 2) % 3); dmaF(ks + 2, (ks + 2) % 3); }

        const short* Wl = (ks % 3 == 0) ? Wb0 : (ks % 3 == 1) ? Wb1 : Wb2;
        const float* Fl = (ks % 3 == 0) ? Fb0 : (ks % 3 == 1) ? Fb1 : Fb2;
        short8 bfA, bfB;
#pragma unroll
        for (int j = 0; j < 8; ++j) {
            bfA[j] = f2bf(Fl[(quad * 8 + j) * 256 + pxA]);
            bfB[j] = f2bf(Fl[(quad * 8 + j) * 256 + pxB]);
        }
#pragma unroll
        for (int mt = 0; mt < 16; ++mt) {
            short8 afrag = *(const short8*)(Wl + mt * 512 + lane * 8);   // shared A
            accA[mt] = __builtin_amdgcn_mfma_f32_16x16x32_bf16(afrag, bfA, accA[mt], 0, 0, 0);
            accB[mt] = __builtin_amdgcn_mfma_f32_16x16x32_bf16(afrag, bfB, accB[mt], 0, 0, 0);
        }
    }

    float ssA = 0.f, ssB = 0.f;
#pragma unroll
    for (int mt = 0; mt < 16; ++mt) {
        float4_ bv = *(const float4_*)(bias + mt * 16 + quad * 4);
#pragma unroll
        for (int r = 0; r < 4; ++r) {
            float vA = accA[mt][r] + bv[r]; accA[mt][r] = vA; ssA += vA * vA;
            float vB = accB[mt][r] + bv[r]; accB[mt][r] = vB; ssB += vB * vB;
        }
    }
    ssA += __shfl_xor(ssA, 16); ssA += __shfl_xor(ssA, 32);
    ssB += __shfl_xor(ssB, 16); ssB += __shfl_xor(ssB, 32);
    const float invA = 1.f / sqrtf(fmaxf(ssA, 1e-24f));
    const float invB = 1.f / sqrtf(fmaxf(ssB, 1e-24f));

    __syncthreads();   // all K-loop LDS reads done; S1/S2/S3 alias the buffers

    {   // u1: 64 px (8 rows x 8 cols)
        const int p1 = t >> 3, co = (t & 7) * 32;
        const int lr = p1 >> 3, lc = p1 & 7;
        const short* src = u1 + ((size_t)(b * 1600 + (8 * R + lr) * 40 + 8 * C + lc)) * CCH + co;
        short* dst = S1 + p1 * SPITCH + co;
#pragma unroll
        for (int j = 0; j < 4; ++j) *(short8*)(dst + j * 8) = *(const short8*)(src + j * 8);
    }
    if (t < 128) {   // u2: 16 px (4 rows x 4 cols)
        const int p2 = t >> 3, co = (t & 7) * 32;
        const int lr = p2 >> 2, lc = p2 & 3;
        const short* src = u2 + ((size_t)(b * 400 + (4 * R + lr) * 20 + 4 * C + lc)) * CCH + co;
        short* dst = S2 + p2 * SPITCH + co;
#pragma unroll
        for (int j = 0; j < 4; ++j) *(short8*)(dst + j * 8) = *(const short8*)(src + j * 8);
    }
    if (t < 32) {    // u3: 4 px (2 rows x 2 cols)
        const int p3 = t >> 3, co = (t & 7) * 32;
        const int lr = p3 >> 1, lc = p3 & 1;
        const short* src = u3 + ((size_t)(b * 100 + (2 * R + lr) * 10 + 2 * C + lc)) * CCH + co;
        short* dst = S3 + p3 * SPITCH + co;
#pragma unroll
        for (int j = 0; j < 4; ++j) *(short8*)(dst + j * 8) = *(const short8*)(src + j * 8);
    }
    __syncthreads();

    const int c1l = wav * 8 + (ln >> 1);
    const int c2l = (wav >> 1) * 4 + (ln >> 2);
    const int c3l = (wav >> 2) * 2 + (ln >> 3);
    float d01 = 0.f, d02 = 0.f, d03 = 0.f;
#pragma unroll
    for (int mt = 0; mt < 16; ++mt) {
        const int ch = mt * 16 + quad * 4;
        short4_ v1 = *(const short4_*)(&S1[c1l * SPITCH + ch]);
        short4_ v2 = *(const short4_*)(&S2[c2l * SPITCH + ch]);
        short4_ v3 = *(const short4_*)(&S3[c3l * SPITCH + ch]);
#pragma unroll
        for (int r = 0; r < 4; ++r) {
            float s = accA[mt][r] * invA + accB[mt][r] * invB;
            d01 += s * bf2f(v1[r]);
            d02 += s * bf2f(v2[r]);
            d03 += s * bf2f(v3[r]);
        }
    }
    {
        float vals[3] = {d01, d02, d03};
#pragma unroll
        for (int p = 0; p < 3; ++p) {
            float v = vals[p];
            v += __shfl_xor(v, 1);  v += __shfl_xor(v, 2);  v += __shfl_xor(v, 4);
            v += __shfl_xor(v, 8);  v += __shfl_xor(v, 16); v += __shfl_xor(v, 32);
            if (lane == 0) redF[wav * 3 + p] = v;
        }
    }

    if (wav < 4) {   // d12/d13 per u1 px: 64 px, 4 lanes each, 64 ch per lane
        const int p1 = wav * 16 + (lane >> 2);   // 0..63
        const int q  = lane & 3;
        const int lr = p1 >> 3, lc = p1 & 7;
        const int par2 = (lr >> 1) * 4 + (lc >> 1);
        const int par3 = (lr >> 2) * 2 + (lc >> 2);
        float e12 = 0.f, e13 = 0.f;
#pragma unroll
        for (int k = 0; k < 16; ++k) {
            const int co = k * 16 + q * 4;
            short4_ a1 = *(const short4_*)(&S1[p1 * SPITCH + co]);
            short4_ a2 = *(const short4_*)(&S2[par2 * SPITCH + co]);
            short4_ a3 = *(const short4_*)(&S3[par3 * SPITCH + co]);
#pragma unroll
            for (int r = 0; r < 4; ++r) {
                float x1 = bf2f(a1[r]);
                e12 += x1 * bf2f(a2[r]);
                e13 += x1 * bf2f(a3[r]);
            }
        }
        float ev[2] = {e12, e13};
#pragma unroll
        for (int p = 0; p < 2; ++p) {
            float v = ev[p];
            v += __shfl_xor(v, 1);  v += __shfl_xor(v, 2);  v += __shfl_xor(v, 4);
            v += __shfl_xor(v, 8);  v += __shfl_xor(v, 16); v += __shfl_xor(v, 32);
            if (lane == 0) redC[wav * 2 + p] = v;
        }
    } else if (wav == 4) {   // d23 per u2 px (16 px, 4 lanes each = full wave)
        const int p2 = lane >> 2;
        const int q  = lane & 3;
        const int lr = p2 >> 2, lc = p2 & 3;
        const int par3 = (lr >> 1) * 2 + (lc >> 1);
        float e23 = 0.f;
#pragma unroll
        for (int k = 0; k < 16; ++k) {
            const int co = k * 16 + q * 4;
            short4_ a2 = *(const short4_*)(&S2[p2 * SPITCH + co]);
            short4_ a3 = *(const short4_*)(&S3[par3 * SPITCH + co]);
#pragma unroll
            for (int r = 0; r < 4; ++r) e23 += bf2f(a2[r]) * bf2f(a3[r]);
        }
        e23 += __shfl_xor(e23, 1);  e23 += __shfl_xor(e23, 2);  e23 += __shfl_xor(e23, 4);
        e23 += __shfl_xor(e23, 8);  e23 += __shfl_xor(e23, 16); e23 += __shfl_xor(e23, 32);
        if (lane == 0) redC[8] = e23;
    }
    __syncthreads();

    if (t < 6) {
        float v;
        if (t < 3) {
            v = 0.f;
#pragma unroll
            for (int w = 0; w < 8; ++w) v += redF[w * 3 + t];
        } else if (t == 3) v = redC[0] + redC[2] + redC[4] + redC[6];   // d12
        else if (t == 4)   v = redC[1] + redC[3] + redC[5] + redC[7];   // d13
        else               v = redC[8];                                 // d23
        partial[((size_t)b * 6 + t) * 25 + c] = v;
    }

    // ---- fused softmax: last block to finish does it (device-scope sync) ----
    __threadfence();
    if (t == 0) {
        unsigned old = atomicAdd(counter, 1u);
        *lastF = (old == 199u) ? 1 : 0;
    }
    __syncthreads();
    if (*lastF) {
        __threadfence();   // acquire: make all blocks' partial stores visible
        if (t < 128) {
            int bb = t >> 4, i = (t >> 2) & 3, j = t & 3;
            float a[4];
#pragma unroll
            for (int jj = 0; jj < 4; ++jj) {
                if (jj == i) { a[jj] = 1.0f; continue; }
                int lo = i < jj ? i : jj;
                int hi = i < jj ? jj : i;
                int pidx;
                if (lo == 0) pidx = hi - 1;
                else if (lo == 1) pidx = 1 + hi;
                else pidx = 5;
                const float* pp = partial + ((size_t)bb * 6 + pidx) * 25;
                float s = 0.f;
                for (int k = 0; k < 25; ++k) s += pp[k];
                int rf = 80 >> lo;
                a[jj] = s / (float)(rf * rf);
            }
            float m = fmaxf(fmaxf(a[0], a[1]), fmaxf(a[2], a[3]));
            float e0 = expf(a[0] - m), e1 = expf(a[1] - m), e2 = expf(a[2] - m), e3 = expf(a[3] - m);
            float sum = e0 + e1 + e2 + e3;
            float ev = (j == 0) ? e0 : (j == 1) ? e1 : (j == 2) ? e2 : e3;
            out[t] = ev / sum;
        }
    }
}

extern "C" void kernel_launch(void* const* d_in, const int* in_sizes, int n_in,
                              void* d_out, int out_size, void* d_ws, size_t ws_size,
                              hipStream_t stream) {
    // setup_inputs dict insertion order: f0,w0,b0, f1,w1,b1, f2,w2,b2, f3,w3,b3
    const float* f[4]  = {(const float*)d_in[0], (const float*)d_in[3],
                          (const float*)d_in[6], (const float*)d_in[9]};
    const float* w[4]  = {(const float*)d_in[1], (const float*)d_in[4],
                          (const float*)d_in[7], (const float*)d_in[10]};
    const float* bs[4] = {(const float*)d_in[2], (const float*)d_in[5],
                          (const float*)d_in[8], (const float*)d_in[11]};

    char* ws = (char*)d_ws;
    size_t off = 0;
    short* u1 = (short*)(ws + off); off += (size_t)8 * CCH * 1600 * sizeof(short);
    short* u2 = (short*)(ws + off); off += (size_t)8 * CCH * 400  * sizeof(short);
    short* u3 = (short*)(ws + off); off += (size_t)8 * CCH * 100  * sizeof(short);
    short* wp = (short*)(ws + off); off += (size_t)4 * 65536 * sizeof(short);  // w0..w3 packed
    float* partial = (float*)(ws + off); off += (size_t)8 * 6 * 25 * sizeof(float);
    unsigned* counter = (unsigned*)(ws + off);

    static int smax_set = 0;
    if (!smax_set) {
        hipFuncSetAttribute(reinterpret_cast<const void*>(proj0_dots),
                            hipFuncAttributeMaxDynamicSharedMemorySize, 147456);
        smax_set = 1;
    }

    pack_w<<<128, 256, 0, stream>>>(w[0], w[1], w[2], w[3], wp, counter);

    proj_small<<<272, 256, 0, stream>>>(f[1], f[2], f[3], wp,
                                        bs[1], bs[2], bs[3],
                                        u1, u2, u3);

    proj0_dots<<<dim3(25, 8), 512, 147456, stream>>>(f[0], wp, bs[0],
                                                     u1, u2, u3, partial,
                                                     counter, (float*)d_out);
}

// Round 7
// 161.604 us; speedup vs baseline: 1.0130x; 1.0130x over previous
//
#include <hip/hip_runtime.h>

// EdgeAttention round 15: A/B isolation of r14's regression (143->164).
//  KEEP: 3-buffer single-barrier K-loops (ps+pd). D(k+2) issued at END of
//    iter k into buf (k+2)%3, whose last reader (iter k-1) was published by
//    iter k's start barrier -> no lgkmcnt(0)+2nd barrier needed. vmcnt(6)
//    counting identical to r13 (6 DMA instr/wave/iter, 1-tile lead).
//  DROP: fused softmax + __threadfence + atomic (suspected culprit: 1600
//    per-wave device-scope fences = L2 writeback storms mid-kernel).
//  RESTORE: __launch_bounds__(512,2) on pd (r14 dropped it; VGPR 72->116),
//    separate softmax4 + plain pack_w (r13 verbatim).
// pd LDS: 3x16K W + 3x32K F = 147456 B dynamic; epilogue S (44.5K) aliases
// the W-buffer region (48K). ps LDS: 3x(16K+8K) = 72 KB static.

#define CCH 256

typedef __attribute__((ext_vector_type(8))) short short8;
typedef __attribute__((ext_vector_type(4))) short short4_;
typedef __attribute__((ext_vector_type(4))) float float4_;

__device__ inline short f2bf(float x) {
    union { float f; unsigned u; } c; c.f = x;
    unsigned u = c.u + 0x7FFFu + ((c.u >> 16) & 1u);
    return (short)(u >> 16);
}
__device__ inline float bf2f(short b) {
    union { unsigned u; float f; } c; c.u = ((unsigned)(unsigned short)b) << 16;
    return c.f;
}

__device__ inline void dma16(const void* g, void* l) {
    __builtin_amdgcn_global_load_lds(
        (const __attribute__((address_space(1))) void*)g,
        (__attribute__((address_space(3))) void*)l, 16, 0, 0);
}

// ---------- pack_w: w0..w3 fp32 -> bf16 fragment-linear (r13 verbatim) ----------
__global__ __launch_bounds__(256) void pack_w(
    const float* __restrict__ w0, const float* __restrict__ w1,
    const float* __restrict__ w2, const float* __restrict__ w3,
    short* __restrict__ wp)
{
    int id = blockIdx.x * 256 + threadIdx.x;     // 0..32767 short8s
    int mtx = id >> 13;
    const float* w = (mtx == 0) ? w0 : (mtx == 1) ? w1 : (mtx == 2) ? w2 : w3;
    int rest = id & 8191;
    int ks = rest >> 10;
    int r2 = rest & 1023;
    int mt = r2 >> 6;
    int fl = r2 & 63;
    int ln = fl & 15, qd = fl >> 4;
    const float* src = w + (size_t)(mt * 16 + ln) * CCH + ks * 32 + qd * 8;
    short8 v;
#pragma unroll
    for (int j = 0; j < 8; ++j) v[j] = f2bf(src[j]);
    *(short8*)(wp + (size_t)id * 8) = v;
}

// ---------- proj_small v4: 3-buffer single-barrier DMA pipeline ----------
// 272 blocks, 4 waves. Block -> (scale, b, 64-px tile). Wave w owns px w*16+ln.
__global__ __launch_bounds__(256) void proj_small(
    const float* __restrict__ f1, const float* __restrict__ f2,
    const float* __restrict__ f3, const short* __restrict__ wp,
    const float* __restrict__ b1, const float* __restrict__ b2,
    const float* __restrict__ b3,
    short* __restrict__ u1, short* __restrict__ u2, short* __restrict__ u3)
{
    __shared__ __align__(16) short Wt0[16 * 512];   // 16 KB each
    __shared__ __align__(16) short Wt1[16 * 512];
    __shared__ __align__(16) short Wt2[16 * 512];
    __shared__ __align__(16) float Ft0[32 * 64];    //  8 KB each
    __shared__ __align__(16) float Ft1[32 * 64];
    __shared__ __align__(16) float Ft2[32 * 64];

    const int blk = blockIdx.x;
    const int t = threadIdx.x;

    int b, tile, L, sidx;
    const float* F; const float* bias; short* U;
    if (blk < 200)      { int r = blk;       b = r / 25; tile = r % 25; L = 1600; F = f1; bias = b1; U = u1; sidx = 1; }
    else if (blk < 256) { int r = blk - 200; b = r / 7;  tile = r % 7;  L = 400;  F = f2; bias = b2; U = u2; sidx = 2; }
    else                { int r = blk - 256; b = r / 2;  tile = r % 2;  L = 100;  F = f3; bias = b3; U = u3; sidx = 3; }

    const int lane = t & 63;
    const int wav  = t >> 6;           // 0..3
    const int ln   = lane & 15;
    const int quad = lane >> 4;
    const int pixbase = tile * 64;
    const float* Fb = F + (size_t)b * CCH * L;
    const short* wps = wp + (size_t)sidx * 65536;

    int gp = pixbase + (lane & 15) * 4;
    if (gp > L - 4) gp = L - 4;
    const int chq = lane >> 4;

    auto dmaW = [&](int ks, int buf) {             // 4 instr/wave (16 KB total)
        short* Wb = (buf == 0) ? Wt0 : (buf == 1) ? Wt1 : Wt2;
#pragma unroll
        for (int m = 0; m < 4; ++m) {
            const int k = wav * 4 + m;                      // mt 0..15
            dma16(wps + (size_t)ks * 8192 + k * 512 + lane * 8, Wb + k * 512);
        }
    };
    auto dmaF = [&](int ks, int buf) {             // 2 instr/wave (8 KB total)
        float* Fl = (buf == 0) ? Ft0 : (buf == 1) ? Ft1 : Ft2;
#pragma unroll
        for (int m = 0; m < 2; ++m) {
            const int k4 = wav * 2 + m;                     // 4-ch group 0..7
            const int ch = k4 * 4 + chq;
            dma16(Fb + (size_t)(ks * 32 + ch) * L + gp, Fl + k4 * 256);
        }
    };

    float4_ acc[16];
#pragma unroll
    for (int i = 0; i < 16; ++i) acc[i] = (float4_){0.f, 0.f, 0.f, 0.f};

    const int fpx = wav * 16 + ln;     // this lane's pixel 0..63

    dmaW(0, 0); dmaF(0, 0);
    dmaW(1, 1); dmaF(1, 1);
#pragma unroll
    for (int ks = 0; ks < 8; ++ks) {
        if (ks < 7) asm volatile("s_waitcnt vmcnt(6)" ::: "memory");
        else        asm volatile("s_waitcnt vmcnt(0)" ::: "memory");
        __builtin_amdgcn_s_barrier();

        const short* Wl = (ks % 3 == 0) ? Wt0 : (ks % 3 == 1) ? Wt1 : Wt2;
        const float* Fl = (ks % 3 == 0) ? Ft0 : (ks % 3 == 1) ? Ft1 : Ft2;
        short8 bfrag;
#pragma unroll
        for (int j = 0; j < 8; ++j)
            bfrag[j] = f2bf(Fl[(quad * 8 + j) * 64 + fpx]);
#pragma unroll
        for (int mt = 0; mt < 16; ++mt) {
            short8 afrag = *(const short8*)(Wl + mt * 512 + lane * 8);
            acc[mt] = __builtin_amdgcn_mfma_f32_16x16x32_bf16(afrag, bfrag, acc[mt], 0, 0, 0);
        }

        // Issue D(ks+2) into buf (ks+2)%3: its last reader was iter ks-1,
        // already published by this iter's start barrier. No drain needed.
        if (ks < 6) { dmaW(ks + 2, (ks + 2) % 3); dmaF(ks + 2, (ks + 2) % 3); }
    }

    float ss = 0.f;
#pragma unroll
    for (int mt = 0; mt < 16; ++mt) {
        float4_ bv = *(const float4_*)(bias + mt * 16 + quad * 4);
#pragma unroll
        for (int r = 0; r < 4; ++r) { float v = acc[mt][r] + bv[r]; acc[mt][r] = v; ss += v * v; }
    }
    ss += __shfl_xor(ss, 16);
    ss += __shfl_xor(ss, 32);
    const float inv = 1.f / sqrtf(fmaxf(ss, 1e-24f));

    const int gpixw = pixbase + fpx;
    if (gpixw < L) {
        short* dst = U + ((size_t)b * L + gpixw) * CCH;
#pragma unroll
        for (int mt = 0; mt < 16; ++mt) {
            short4_ v;
#pragma unroll
            for (int r = 0; r < 4; ++r) v[r] = f2bf(acc[mt][r] * inv);
            *(short4_*)(dst + mt * 16 + quad * 4) = v;
        }
    }
}

// ---------- proj0_dots v7: 3-buffer single-barrier pipeline (no fused tail) ------
#define SPITCH 264
__global__ __launch_bounds__(512, 2) void proj0_dots(
    const float* __restrict__ F, const short* __restrict__ wp,
    const float* __restrict__ bias,
    const short* __restrict__ u1, const short* __restrict__ u2,
    const short* __restrict__ u3,
    float* __restrict__ partial)
{
    extern __shared__ __align__(16) char smem[];  // 147456 B dynamic
    short* Wb0 = (short*)smem;                    // 16 KB W bufs
    short* Wb1 = (short*)(smem + 16384);
    short* Wb2 = (short*)(smem + 32768);
    float* Fb0 = (float*)(smem + 49152);          // 32 KB F bufs
    float* Fb1 = (float*)(smem + 81920);
    float* Fb2 = (float*)(smem + 114688);         // ends 147456
    short* S1 = (short*)smem;                     // 64 px * 264 * 2 = 33792 B
    short* S2 = (short*)(smem + 33792);           // 16 px           =  8448 B
    short* S3 = (short*)(smem + 42240);           //  4 px           =  2112 B
    float* redF = (float*)(smem + 44352);         // [8][3]
    float* redC = (float*)(smem + 44448);         // [9]

    const int c  = blockIdx.x;         // 0..24
    const int b  = blockIdx.y;
    const int R  = c / 5, C = c - R * 5;
    const int t  = threadIdx.x;
    const int lane = t & 63;
    const int wav  = t >> 6;           // 0..7
    const int ln   = lane & 15;
    const int quad = lane >> 4;
    const float* Fbase = F + (size_t)b * CCH * 6400;

    auto dmaW = [&](int ks, int buf) {             // 2 instr/wave (16 KB total)
        short* Wb = (buf == 0) ? Wb0 : (buf == 1) ? Wb1 : Wb2;
#pragma unroll
        for (int m = 0; m < 2; ++m) {
            const int k = wav * 2 + m;                      // 0..15
            dma16(wp + (size_t)ks * 8192 + k * 512 + lane * 8, Wb + k * 512);
        }
    };
    auto dmaF = [&](int ks, int buf) {             // 4 instr/wave (32 KB total)
        float* Fl = (buf == 0) ? Fb0 : (buf == 1) ? Fb1 : Fb2;
        const int gpx = (16 * R + (lane >> 2)) * 80 + 16 * C + (lane & 3) * 4;
#pragma unroll
        for (int m = 0; m < 4; ++m) {
            const int k = wav * 4 + m;                      // channel 0..31
            dma16(Fbase + (size_t)(ks * 32 + k) * 6400 + gpx, Fl + k * 256);
        }
    };

    float4_ accA[16], accB[16];
#pragma unroll
    for (int i = 0; i < 16; ++i) {
        accA[i] = (float4_){0.f, 0.f, 0.f, 0.f};
        accB[i] = (float4_){0.f, 0.f, 0.f, 0.f};
    }

    const int pxA = wav * 32 + ln;     // fine row 2w, col ln
    const int pxB = pxA + 16;          // fine row 2w+1

    dmaW(0, 0); dmaF(0, 0);
    dmaW(1, 1); dmaF(1, 1);
#pragma unroll
    for (int ks = 0; ks < 8; ++ks) {
        if (ks < 7) asm volatile("s_waitcnt vmcnt(6)" ::: "memory");
        else        asm volatile("s_waitcnt vmcnt(0)" ::: "memory");
        __builtin_amdgcn_s_barrier();

        const short* Wl = (ks % 3 == 0) ? Wb0 : (ks % 3 == 1) ? Wb1 : Wb2;
        const float* Fl = (ks % 3 == 0) ? Fb0 : (ks % 3 == 1) ? Fb1 : Fb2;
        short8 bfA, bfB;
#pragma unroll
        for (int j = 0; j < 8; ++j) {
            bfA[j] = f2bf(Fl[(quad * 8 + j) * 256 + pxA]);
            bfB[j] = f2bf(Fl[(quad * 8 + j) * 256 + pxB]);
        }
#pragma unroll
        for (int mt = 0; mt < 16; ++mt) {
            short8 afrag = *(const short8*)(Wl + mt * 512 + lane * 8);   // shared A
            accA[mt] = __builtin_amdgcn_mfma_f32_16x16x32_bf16(afrag, bfA, accA[mt], 0, 0, 0);
            accB[mt] = __builtin_amdgcn_mfma_f32_16x16x32_bf16(afrag, bfB, accB[mt], 0, 0, 0);
        }

        if (ks < 6) { dmaW(ks + 2, (ks + 2) % 3); dmaF(ks + 2, (ks + 2) % 3); }
    }

    float ssA = 0.f, ssB = 0.f;
#pragma unroll
    for (int mt = 0; mt < 16; ++mt) {
        float4_ bv = *(const float4_*)(bias + mt * 16 + quad * 4);
#pragma unroll
        for (int r = 0; r < 4; ++r) {
            float vA = accA[mt][r] + bv[r]; accA[mt][r] = vA; ssA += vA * vA;
            float vB = accB[mt][r] + bv[r]; accB[mt][r] = vB; ssB += vB * vB;
        }
    }
    ssA += __shfl_xor(ssA, 16); ssA += __shfl_xor(ssA, 32);
    ssB += __shfl_xor(ssB, 16); ssB += __shfl_xor(ssB, 32);
    const float invA = 1.f / sqrtf(fmaxf(ssA, 1e-24f));
    const float invB = 1.f / sqrtf(fmaxf(ssB, 1e-24f));

    __syncthreads();   // all K-loop LDS reads done; S1/S2/S3 alias the W bufs

    {   // u1: 64 px (8 rows x 8 cols)
        const int p1 = t >> 3, co = (t & 7) * 32;
        const int lr = p1 >> 3, lc = p1 & 7;
        const short* src = u1 + ((size_t)(b * 1600 + (8 * R + lr) * 40 + 8 * C + lc)) * CCH + co;
        short* dst = S1 + p1 * SPITCH + co;
#pragma unroll
        for (int j = 0; j < 4; ++j) *(short8*)(dst + j * 8) = *(const short8*)(src + j * 8);
    }
    if (t < 128) {   // u2: 16 px (4 rows x 4 cols)
        const int p2 = t >> 3, co = (t & 7) * 32;
        const int lr = p2 >> 2, lc = p2 & 3;
        const short* src = u2 + ((size_t)(b * 400 + (4 * R + lr) * 20 + 4 * C + lc)) * CCH + co;
        short* dst = S2 + p2 * SPITCH + co;
#pragma unroll
        for (int j = 0; j < 4; ++j) *(short8*)(dst + j * 8) = *(const short8*)(src + j * 8);
    }
    if (t < 32) {    // u3: 4 px (2 rows x 2 cols)
        const int p3 = t >> 3, co = (t & 7) * 32;
        const int lr = p3 >> 1, lc = p3 & 1;
        const short* src = u3 + ((size_t)(b * 100 + (2 * R + lr) * 10 + 2 * C + lc)) * CCH + co;
        short* dst = S3 + p3 * SPITCH + co;
#pragma unroll
        for (int j = 0; j < 4; ++j) *(short8*)(dst + j * 8) = *(const short8*)(src + j * 8);
    }
    __syncthreads();

    const int c1l = wav * 8 + (ln >> 1);
    const int c2l = (wav >> 1) * 4 + (ln >> 2);
    const int c3l = (wav >> 2) * 2 + (ln >> 3);
    float d01 = 0.f, d02 = 0.f, d03 = 0.f;
#pragma unroll
    for (int mt = 0; mt < 16; ++mt) {
        const int ch = mt * 16 + quad * 4;
        short4_ v1 = *(const short4_*)(&S1[c1l * SPITCH + ch]);
        short4_ v2 = *(const short4_*)(&S2[c2l * SPITCH + ch]);
        short4_ v3 = *(const short4_*)(&S3[c3l * SPITCH + ch]);
#pragma unroll
        for (int r = 0; r < 4; ++r) {
            float s = accA[mt][r] * invA + accB[mt][r] * invB;
            d01 += s * bf2f(v1[r]);
            d02 += s * bf2f(v2[r]);
            d03 += s * bf2f(v3[r]);
        }
    }
    {
        float vals[3] = {d01, d02, d03};
#pragma unroll
        for (int p = 0; p < 3; ++p) {
            float v = vals[p];
            v += __shfl_xor(v, 1);  v += __shfl_xor(v, 2);  v += __shfl_xor(v, 4);
            v += __shfl_xor(v, 8);  v += __shfl_xor(v, 16); v += __shfl_xor(v, 32);
            if (lane == 0) redF[wav * 3 + p] = v;
        }
    }

    if (wav < 4) {   // d12/d13 per u1 px: 64 px, 4 lanes each, 64 ch per lane
        const int p1 = wav * 16 + (lane >> 2);   // 0..63
        const int q  = lane & 3;
        const int lr = p1 >> 3, lc = p1 & 7;
        const int par2 = (lr >> 1) * 4 + (lc >> 1);
        const int par3 = (lr >> 2) * 2 + (lc >> 2);
        float e12 = 0.f, e13 = 0.f;
#pragma unroll
        for (int k = 0; k < 16; ++k) {
            const int co = k * 16 + q * 4;
            short4_ a1 = *(const short4_*)(&S1[p1 * SPITCH + co]);
            short4_ a2 = *(const short4_*)(&S2[par2 * SPITCH + co]);
            short4_ a3 = *(const short4_*)(&S3[par3 * SPITCH + co]);
#pragma unroll
            for (int r = 0; r < 4; ++r) {
                float x1 = bf2f(a1[r]);
                e12 += x1 * bf2f(a2[r]);
                e13 += x1 * bf2f(a3[r]);
            }
        }
        float ev[2] = {e12, e13};
#pragma unroll
        for (int p = 0; p < 2; ++p) {
            float v = ev[p];
            v += __shfl_xor(v, 1);  v += __shfl_xor(v, 2);  v += __shfl_xor(v, 4);
            v += __shfl_xor(v, 8);  v += __shfl_xor(v, 16); v += __shfl_xor(v, 32);
            if (lane == 0) redC[wav * 2 + p] = v;
        }
    } else if (wav == 4) {   // d23 per u2 px (16 px, 4 lanes each = full wave)
        const int p2 = lane >> 2;
        const int q  = lane & 3;
        const int lr = p2 >> 2, lc = p2 & 3;
        const int par3 = (lr >> 1) * 2 + (lc >> 1);
        float e23 = 0.f;
#pragma unroll
        for (int k = 0; k < 16; ++k) {
            const int co = k * 16 + q * 4;
            short4_ a2 = *(const short4_*)(&S2[p2 * SPITCH + co]);
            short4_ a3 = *(const short4_*)(&S3[par3 * SPITCH + co]);
#pragma unroll
            for (int r = 0; r < 4; ++r) e23 += bf2f(a2[r]) * bf2f(a3[r]);
        }
        e23 += __shfl_xor(e23, 1);  e23 += __shfl_xor(e23, 2);  e23 += __shfl_xor(e23, 4);
        e23 += __shfl_xor(e23, 8);  e23 += __shfl_xor(e23, 16); e23 += __shfl_xor(e23, 32);
        if (lane == 0) redC[8] = e23;
    }
    __syncthreads();

    if (t < 6) {
        float v;
        if (t < 3) {
            v = 0.f;
#pragma unroll
            for (int w = 0; w < 8; ++w) v += redF[w * 3 + t];
        } else if (t == 3) v = redC[0] + redC[2] + redC[4] + redC[6];   // d12
        else if (t == 4)   v = redC[1] + redC[3] + redC[5] + redC[7];   // d13
        else               v = redC[8];                                 // d23
        partial[((size_t)b * 6 + t) * 25 + c] = v;
    }
}

// ---------- Softmax over j for each (b,i) row (sums 25 cell partials) ----------
__global__ void softmax4(const float* __restrict__ partial, float* __restrict__ out) {
    int t = threadIdx.x;
    if (t >= 128) return;
    int b = t >> 4, i = (t >> 2) & 3, j = t & 3;
    float a[4];
#pragma unroll
    for (int jj = 0; jj < 4; ++jj) {
        if (jj == i) { a[jj] = 1.0f; continue; }
        int lo = i < jj ? i : jj;
        int hi = i < jj ? jj : i;
        int pidx;
        if (lo == 0) pidx = hi - 1;          // (0,1)=0 (0,2)=1 (0,3)=2
        else if (lo == 1) pidx = 1 + hi;     // (1,2)=3 (1,3)=4
        else pidx = 5;                       // (2,3)=5
        const float* pp = partial + ((size_t)b * 6 + pidx) * 25;
        float s = 0.f;
        for (int k = 0; k < 25; ++k) s += pp[k];
        int rf = 80 >> lo;
        a[jj] = s / (float)(rf * rf);
    }
    float m = fmaxf(fmaxf(a[0], a[1]), fmaxf(a[2], a[3]));
    float e0 = expf(a[0] - m), e1 = expf(a[1] - m), e2 = expf(a[2] - m), e3 = expf(a[3] - m);
    float sum = e0 + e1 + e2 + e3;
    float ev = (j == 0) ? e0 : (j == 1) ? e1 : (j == 2) ? e2 : e3;
    out[t] = ev / sum;
}

extern "C" void kernel_launch(void* const* d_in, const int* in_sizes, int n_in,
                              void* d_out, int out_size, void* d_ws, size_t ws_size,
                              hipStream_t stream) {
    // setup_inputs dict insertion order: f0,w0,b0, f1,w1,b1, f2,w2,b2, f3,w3,b3
    const float* f[4]  = {(const float*)d_in[0], (const float*)d_in[3],
                          (const float*)d_in[6], (const float*)d_in[9]};
    const float* w[4]  = {(const float*)d_in[1], (const float*)d_in[4],
                          (const float*)d_in[7], (const float*)d_in[10]};
    const float* bs[4] = {(const float*)d_in[2], (const float*)d_in[5],
                          (const float*)d_in[8], (const float*)d_in[11]};

    char* ws = (char*)d_ws;
    size_t off = 0;
    short* u1 = (short*)(ws + off); off += (size_t)8 * CCH * 1600 * sizeof(short);
    short* u2 = (short*)(ws + off); off += (size_t)8 * CCH * 400  * sizeof(short);
    short* u3 = (short*)(ws + off); off += (size_t)8 * CCH * 100  * sizeof(short);
    short* wp = (short*)(ws + off); off += (size_t)4 * 65536 * sizeof(short);  // w0..w3 packed
    float* partial = (float*)(ws + off);   // 8*6*25 floats

    static int smax_set = 0;
    if (!smax_set) {
        hipFuncSetAttribute(reinterpret_cast<const void*>(proj0_dots),
                            hipFuncAttributeMaxDynamicSharedMemorySize, 147456);
        smax_set = 1;
    }

    pack_w<<<128, 256, 0, stream>>>(w[0], w[1], w[2], w[3], wp);

    proj_small<<<272, 256, 0, stream>>>(f[1], f[2], f[3], wp,
                                        bs[1], bs[2], bs[3],
                                        u1, u2, u3);

    proj0_dots<<<dim3(25, 8), 512, 147456, stream>>>(f[0], wp, bs[0],
                                                     u1, u2, u3, partial);

    softmax4<<<1, 128, 0, stream>>>(partial, (float*)d_out);
}

// Round 8
// 141.819 us; speedup vs baseline: 1.1543x; 1.1395x over previous
//
#include <hip/hip_runtime.h>

// EdgeAttention round 16: REVERT to r13 verbatim (measured best, 143.1 us).
// r14 (3-buf + fused softmax): 163.7. r15 (3-buf only): 161.6, WRITE_SIZE
// 73KB->22.8MB = VGPR spill at the launch_bounds(512,2) 128-reg cap from the
// 3-buffer rotation's extended live ranges. The 2-buffer/2-barrier pipeline
// is the shape the allocator schedules spill-free. All other r13 components
// (pack_w once, ps counted-vmcnt DMA, pd 256-px tile, SPITCH=264 epilogue,
// separate softmax4) were individually validated on the ladder r9->r13.

#define CCH 256

typedef __attribute__((ext_vector_type(8))) short short8;
typedef __attribute__((ext_vector_type(4))) short short4_;
typedef __attribute__((ext_vector_type(4))) float float4_;

__device__ inline short f2bf(float x) {
    union { float f; unsigned u; } c; c.f = x;
    unsigned u = c.u + 0x7FFFu + ((c.u >> 16) & 1u);
    return (short)(u >> 16);
}
__device__ inline float bf2f(short b) {
    union { unsigned u; float f; } c; c.u = ((unsigned)(unsigned short)b) << 16;
    return c.f;
}

__device__ inline void dma16(const void* g, void* l) {
    __builtin_amdgcn_global_load_lds(
        (const __attribute__((address_space(1))) void*)g,
        (__attribute__((address_space(3))) void*)l, 16, 0, 0);
}

// ---------- pack_w: w0..w3 fp32 -> bf16 fragment-linear ----------
// Layout (per matrix, 65536 shorts): pos = ks*8192 + mt*512 + lane*8 + e, where
// short = w[(mt*16 + (lane&15))*256 + ks*32 + (lane>>4)*8 + e]. Matches the
// MFMA A-fragment read afrag = Wl[mt*512 + lane*8] used by ps and pd.
__global__ __launch_bounds__(256) void pack_w(
    const float* __restrict__ w0, const float* __restrict__ w1,
    const float* __restrict__ w2, const float* __restrict__ w3,
    short* __restrict__ wp)
{
    int id = blockIdx.x * 256 + threadIdx.x;     // 0..32767 short8s
    int mtx = id >> 13;
    const float* w = (mtx == 0) ? w0 : (mtx == 1) ? w1 : (mtx == 2) ? w2 : w3;
    int rest = id & 8191;
    int ks = rest >> 10;
    int r2 = rest & 1023;
    int mt = r2 >> 6;
    int fl = r2 & 63;
    int ln = fl & 15, qd = fl >> 4;
    const float* src = w + (size_t)(mt * 16 + ln) * CCH + ks * 32 + qd * 8;
    short8 v;
#pragma unroll
    for (int j = 0; j < 8; ++j) v[j] = f2bf(src[j]);
    *(short8*)(wp + (size_t)id * 8) = v;
}

// ---------- proj_small v2: counted-vmcnt DMA pipeline (pd-r11 skeleton) ------
// 272 blocks, 4 waves. Block -> (scale, b, 64-px tile). Wave w owns px w*16+ln.
// LDS: W dbuf 2x16KB (fragment-linear bf16) + F dbuf 2x8KB ([32ch][64px] fp32).
__global__ __launch_bounds__(256) void proj_small(
    const float* __restrict__ f1, const float* __restrict__ f2,
    const float* __restrict__ f3, const short* __restrict__ wp,
    const float* __restrict__ b1, const float* __restrict__ b2,
    const float* __restrict__ b3,
    short* __restrict__ u1, short* __restrict__ u2, short* __restrict__ u3)
{
    __shared__ __align__(16) short Wt0[16 * 512];   // 16 KB
    __shared__ __align__(16) short Wt1[16 * 512];
    __shared__ __align__(16) float Ft0[32 * 64];    //  8 KB
    __shared__ __align__(16) float Ft1[32 * 64];

    const int blk = blockIdx.x;
    const int t = threadIdx.x;

    int b, tile, L, sidx;
    const float* F; const float* bias; short* U;
    if (blk < 200)      { int r = blk;       b = r / 25; tile = r % 25; L = 1600; F = f1; bias = b1; U = u1; sidx = 1; }
    else if (blk < 256) { int r = blk - 200; b = r / 7;  tile = r % 7;  L = 400;  F = f2; bias = b2; U = u2; sidx = 2; }
    else                { int r = blk - 256; b = r / 2;  tile = r % 2;  L = 100;  F = f3; bias = b3; U = u3; sidx = 3; }

    const int lane = t & 63;
    const int wav  = t >> 6;           // 0..3
    const int ln   = lane & 15;
    const int quad = lane >> 4;
    const int pixbase = tile * 64;
    const float* Fb = F + (size_t)b * CCH * L;
    const short* wps = wp + (size_t)sidx * 65536;

    // Per-lane F source px chunk (clamped to stay in-buffer on edge tiles).
    int gp = pixbase + (lane & 15) * 4;
    if (gp > L - 4) gp = L - 4;
    const int chq = lane >> 4;         // ch offset within 4-ch group

    auto dmaW = [&](int ks, int buf) {             // 4 instr/wave (16 KB total)
        short* Wb = buf ? Wt1 : Wt0;
#pragma unroll
        for (int m = 0; m < 4; ++m) {
            const int k = wav * 4 + m;                      // mt 0..15
            dma16(wps + (size_t)ks * 8192 + k * 512 + lane * 8, Wb + k * 512);
        }
    };
    auto dmaF = [&](int ks, int buf) {             // 2 instr/wave (8 KB total)
        float* Fb_l = buf ? Ft1 : Ft0;
#pragma unroll
        for (int m = 0; m < 2; ++m) {
            const int k4 = wav * 2 + m;                     // 4-ch group 0..7
            const int ch = k4 * 4 + chq;
            dma16(Fb + (size_t)(ks * 32 + ch) * L + gp, Fb_l + k4 * 256);
        }
    };

    float4_ acc[16];
#pragma unroll
    for (int i = 0; i < 16; ++i) acc[i] = (float4_){0.f, 0.f, 0.f, 0.f};

    const int fpx = wav * 16 + ln;     // this lane's pixel 0..63

    dmaW(0, 0); dmaF(0, 0);
    dmaW(1, 1); dmaF(1, 1);
#pragma unroll
    for (int ks = 0; ks < 8; ++ks) {
        if (ks < 7) asm volatile("s_waitcnt vmcnt(6)" ::: "memory");
        else        asm volatile("s_waitcnt vmcnt(0)" ::: "memory");
        __builtin_amdgcn_s_barrier();

        const short* Wl = (ks & 1) ? Wt1 : Wt0;
        const float* Fl = (ks & 1) ? Ft1 : Ft0;
        short8 bfrag;
#pragma unroll
        for (int j = 0; j < 8; ++j)
            bfrag[j] = f2bf(Fl[(quad * 8 + j) * 64 + fpx]);
#pragma unroll
        for (int mt = 0; mt < 16; ++mt) {
            short8 afrag = *(const short8*)(Wl + mt * 512 + lane * 8);
            acc[mt] = __builtin_amdgcn_mfma_f32_16x16x32_bf16(afrag, bfrag, acc[mt], 0, 0, 0);
        }

        if (ks < 6) {
            asm volatile("s_waitcnt lgkmcnt(0)" ::: "memory");
            __builtin_amdgcn_s_barrier();
            dmaW(ks + 2, ks & 1); dmaF(ks + 2, ks & 1);
        }
    }

    float ss = 0.f;
#pragma unroll
    for (int mt = 0; mt < 16; ++mt) {
        float4_ bv = *(const float4_*)(bias + mt * 16 + quad * 4);
#pragma unroll
        for (int r = 0; r < 4; ++r) { float v = acc[mt][r] + bv[r]; acc[mt][r] = v; ss += v * v; }
    }
    ss += __shfl_xor(ss, 16);
    ss += __shfl_xor(ss, 32);
    const float inv = 1.f / sqrtf(fmaxf(ss, 1e-24f));

    const int gpixw = pixbase + fpx;
    if (gpixw < L) {
        short* dst = U + ((size_t)b * L + gpixw) * CCH;
#pragma unroll
        for (int mt = 0; mt < 16; ++mt) {
            short4_ v;
#pragma unroll
            for (int r = 0; r < 4; ++r) v[r] = f2bf(acc[mt][r] * inv);
            *(short4_*)(dst + mt * 16 + quad * 4) = v;
        }
    }
}

// ---------- proj0_dots (r11/r13 verbatim): 256-px tile, counted-vmcnt pipeline ------
#define SPITCH 264  // epilogue staging pitch: 528 B row stride, bank-spread
__global__ __launch_bounds__(512, 2) void proj0_dots(
    const float* __restrict__ F, const short* __restrict__ wp,
    const float* __restrict__ bias,
    const short* __restrict__ u1, const short* __restrict__ u2,
    const short* __restrict__ u3,
    float* __restrict__ partial)
{
    extern __shared__ __align__(16) char smem[];     // 98304 B dynamic
    short* Wb0 = (short*)smem;                    // 16 KB bf16 W slice, buf 0
    short* Wb1 = (short*)(smem + 16384);          // buf 1
    float* Fb0 = (float*)(smem + 32768);          // 32 KB fp32 F slice [32ch][256px]
    float* Fb1 = (float*)(smem + 65536);          // buf 1 (ends at 98304)
    short* S1 = (short*)smem;                     // 64 px * 264 * 2 = 33792 B
    short* S2 = (short*)(smem + 33792);           // 16 px           =  8448 B
    short* S3 = (short*)(smem + 42240);           //  4 px           =  2112 B
    float* redF = (float*)(smem + 44352);         // [8][3]
    float* redC = (float*)(smem + 44448);         // [9]

    const int c  = blockIdx.x;         // 0..24
    const int b  = blockIdx.y;
    const int R  = c / 5, C = c - R * 5;
    const int t  = threadIdx.x;
    const int lane = t & 63;
    const int wav  = t >> 6;           // 0..7
    const int ln   = lane & 15;
    const int quad = lane >> 4;
    const float* Fbase = F + (size_t)b * CCH * 6400;

    auto dmaW = [&](int ks, int buf) {             // 2 instr/wave (16 KB total)
        short* Wb = buf ? Wb1 : Wb0;
#pragma unroll
        for (int m = 0; m < 2; ++m) {
            const int k = wav * 2 + m;                      // 0..15
            dma16(wp + (size_t)ks * 8192 + k * 512 + lane * 8, Wb + k * 512);
        }
    };
    auto dmaF = [&](int ks, int buf) {             // 4 instr/wave (32 KB total)
        float* Fb = buf ? Fb1 : Fb0;
        const int gpx = (16 * R + (lane >> 2)) * 80 + 16 * C + (lane & 3) * 4;
#pragma unroll
        for (int m = 0; m < 4; ++m) {
            const int k = wav * 4 + m;                      // channel 0..31
            dma16(Fbase + (size_t)(ks * 32 + k) * 6400 + gpx, Fb + k * 256);
        }
    };

    float4_ accA[16], accB[16];
#pragma unroll
    for (int i = 0; i < 16; ++i) {
        accA[i] = (float4_){0.f, 0.f, 0.f, 0.f};
        accB[i] = (float4_){0.f, 0.f, 0.f, 0.f};
    }

    const int pxA = wav * 32 + ln;     // fine row 2w, col ln
    const int pxB = pxA + 16;          // fine row 2w+1

    dmaW(0, 0); dmaF(0, 0);
    dmaW(1, 1); dmaF(1, 1);
#pragma unroll
    for (int ks = 0; ks < 8; ++ks) {
        if (ks < 7) asm volatile("s_waitcnt vmcnt(6)" ::: "memory");
        else        asm volatile("s_waitcnt vmcnt(0)" ::: "memory");
        __builtin_amdgcn_s_barrier();

        const short* Wl = (ks & 1) ? Wb1 : Wb0;
        const float* Fl = (ks & 1) ? Fb1 : Fb0;
        short8 bfA, bfB;
#pragma unroll
        for (int j = 0; j < 8; ++j) {
            bfA[j] = f2bf(Fl[(quad * 8 + j) * 256 + pxA]);
            bfB[j] = f2bf(Fl[(quad * 8 + j) * 256 + pxB]);
        }
#pragma unroll
        for (int mt = 0; mt < 16; ++mt) {
            short8 afrag = *(const short8*)(Wl + mt * 512 + lane * 8);   // shared A
            accA[mt] = __builtin_amdgcn_mfma_f32_16x16x32_bf16(afrag, bfA, accA[mt], 0, 0, 0);
            accB[mt] = __builtin_amdgcn_mfma_f32_16x16x32_bf16(afrag, bfB, accB[mt], 0, 0, 0);
        }

        if (ks < 6) {
            asm volatile("s_waitcnt lgkmcnt(0)" ::: "memory");
            __builtin_amdgcn_s_barrier();
            dmaW(ks + 2, ks & 1); dmaF(ks + 2, ks & 1);
        }
    }

    float ssA = 0.f, ssB = 0.f;
#pragma unroll
    for (int mt = 0; mt < 16; ++mt) {
        float4_ bv = *(const float4_*)(bias + mt * 16 + quad * 4);
#pragma unroll
        for (int r = 0; r < 4; ++r) {
            float vA = accA[mt][r] + bv[r]; accA[mt][r] = vA; ssA += vA * vA;
            float vB = accB[mt][r] + bv[r]; accB[mt][r] = vB; ssB += vB * vB;
        }
    }
    ssA += __shfl_xor(ssA, 16); ssA += __shfl_xor(ssA, 32);
    ssB += __shfl_xor(ssB, 16); ssB += __shfl_xor(ssB, 32);
    const float invA = 1.f / sqrtf(fmaxf(ssA, 1e-24f));
    const float invB = 1.f / sqrtf(fmaxf(ssB, 1e-24f));

    __syncthreads();   // S1/S2/S3 alias the K-loop buffers (vmcnt already 0)

    {   // u1: 64 px (8 rows x 8 cols)
        const int p1 = t >> 3, co = (t & 7) * 32;
        const int lr = p1 >> 3, lc = p1 & 7;
        const short* src = u1 + ((size_t)(b * 1600 + (8 * R + lr) * 40 + 8 * C + lc)) * CCH + co;
        short* dst = S1 + p1 * SPITCH + co;
#pragma unroll
        for (int j = 0; j < 4; ++j) *(short8*)(dst + j * 8) = *(const short8*)(src + j * 8);
    }
    if (t < 128) {   // u2: 16 px (4 rows x 4 cols)
        const int p2 = t >> 3, co = (t & 7) * 32;
        const int lr = p2 >> 2, lc = p2 & 3;
        const short* src = u2 + ((size_t)(b * 400 + (4 * R + lr) * 20 + 4 * C + lc)) * CCH + co;
        short* dst = S2 + p2 * SPITCH + co;
#pragma unroll
        for (int j = 0; j < 4; ++j) *(short8*)(dst + j * 8) = *(const short8*)(src + j * 8);
    }
    if (t < 32) {    // u3: 4 px (2 rows x 2 cols)
        const int p3 = t >> 3, co = (t & 7) * 32;
        const int lr = p3 >> 1, lc = p3 & 1;
        const short* src = u3 + ((size_t)(b * 100 + (2 * R + lr) * 10 + 2 * C + lc)) * CCH + co;
        short* dst = S3 + p3 * SPITCH + co;
#pragma unroll
        for (int j = 0; j < 4; ++j) *(short8*)(dst + j * 8) = *(const short8*)(src + j * 8);
    }
    __syncthreads();

    const int c1l = wav * 8 + (ln >> 1);
    const int c2l = (wav >> 1) * 4 + (ln >> 2);
    const int c3l = (wav >> 2) * 2 + (ln >> 3);
    float d01 = 0.f, d02 = 0.f, d03 = 0.f;
#pragma unroll
    for (int mt = 0; mt < 16; ++mt) {
        const int ch = mt * 16 + quad * 4;
        short4_ v1 = *(const short4_*)(&S1[c1l * SPITCH + ch]);
        short4_ v2 = *(const short4_*)(&S2[c2l * SPITCH + ch]);
        short4_ v3 = *(const short4_*)(&S3[c3l * SPITCH + ch]);
#pragma unroll
        for (int r = 0; r < 4; ++r) {
            float s = accA[mt][r] * invA + accB[mt][r] * invB;
            d01 += s * bf2f(v1[r]);
            d02 += s * bf2f(v2[r]);
            d03 += s * bf2f(v3[r]);
        }
    }
    {
        float vals[3] = {d01, d02, d03};
#pragma unroll
        for (int p = 0; p < 3; ++p) {
            float v = vals[p];
            v += __shfl_xor(v, 1);  v += __shfl_xor(v, 2);  v += __shfl_xor(v, 4);
            v += __shfl_xor(v, 8);  v += __shfl_xor(v, 16); v += __shfl_xor(v, 32);
            if (lane == 0) redF[wav * 3 + p] = v;
        }
    }

    if (wav < 4) {   // d12/d13 per u1 px: 64 px, 4 lanes each, 64 ch per lane
        const int p1 = wav * 16 + (lane >> 2);   // 0..63
        const int q  = lane & 3;
        const int lr = p1 >> 3, lc = p1 & 7;
        const int par2 = (lr >> 1) * 4 + (lc >> 1);
        const int par3 = (lr >> 2) * 2 + (lc >> 2);
        float e12 = 0.f, e13 = 0.f;
#pragma unroll
        for (int k = 0; k < 16; ++k) {
            const int co = k * 16 + q * 4;
            short4_ a1 = *(const short4_*)(&S1[p1 * SPITCH + co]);
            short4_ a2 = *(const short4_*)(&S2[par2 * SPITCH + co]);
            short4_ a3 = *(const short4_*)(&S3[par3 * SPITCH + co]);
#pragma unroll
            for (int r = 0; r < 4; ++r) {
                float x1 = bf2f(a1[r]);
                e12 += x1 * bf2f(a2[r]);
                e13 += x1 * bf2f(a3[r]);
            }
        }
        float ev[2] = {e12, e13};
#pragma unroll
        for (int p = 0; p < 2; ++p) {
            float v = ev[p];
            v += __shfl_xor(v, 1);  v += __shfl_xor(v, 2);  v += __shfl_xor(v, 4);
            v += __shfl_xor(v, 8);  v += __shfl_xor(v, 16); v += __shfl_xor(v, 32);
            if (lane == 0) redC[wav * 2 + p] = v;
        }
    } else if (wav == 4) {   // d23 per u2 px (16 px, 4 lanes each = full wave)
        const int p2 = lane >> 2;
        const int q  = lane & 3;
        const int lr = p2 >> 2, lc = p2 & 3;
        const int par3 = (lr >> 1) * 2 + (lc >> 1);
        float e23 = 0.f;
#pragma unroll
        for (int k = 0; k < 16; ++k) {
            const int co = k * 16 + q * 4;
            short4_ a2 = *(const short4_*)(&S2[p2 * SPITCH + co]);
            short4_ a3 = *(const short4_*)(&S3[par3 * SPITCH + co]);
#pragma unroll
            for (int r = 0; r < 4; ++r) e23 += bf2f(a2[r]) * bf2f(a3[r]);
        }
        e23 += __shfl_xor(e23, 1);  e23 += __shfl_xor(e23, 2);  e23 += __shfl_xor(e23, 4);
        e23 += __shfl_xor(e23, 8);  e23 += __shfl_xor(e23, 16); e23 += __shfl_xor(e23, 32);
        if (lane == 0) redC[8] = e23;
    }
    __syncthreads();

    if (t < 6) {
        float v;
        if (t < 3) {
            v = 0.f;
#pragma unroll
            for (int w = 0; w < 8; ++w) v += redF[w * 3 + t];
        } else if (t == 3) v = redC[0] + redC[2] + redC[4] + redC[6];   // d12
        else if (t == 4)   v = redC[1] + redC[3] + redC[5] + redC[7];   // d13
        else               v = redC[8];                                 // d23
        partial[((size_t)b * 6 + t) * 25 + c] = v;
    }
}

// ---------- Softmax over j for each (b,i) row (sums 25 cell partials) ----------
__global__ void softmax4(const float* __restrict__ partial, float* __restrict__ out) {
    int t = threadIdx.x;
    if (t >= 128) return;
    int b = t >> 4, i = (t >> 2) & 3, j = t & 3;
    float a[4];
#pragma unroll
    for (int jj = 0; jj < 4; ++jj) {
        if (jj == i) { a[jj] = 1.0f; continue; }
        int lo = i < jj ? i : jj;
        int hi = i < jj ? jj : i;
        int pidx;
        if (lo == 0) pidx = hi - 1;          // (0,1)=0 (0,2)=1 (0,3)=2
        else if (lo == 1) pidx = 1 + hi;     // (1,2)=3 (1,3)=4
        else pidx = 5;                       // (2,3)=5
        const float* pp = partial + ((size_t)b * 6 + pidx) * 25;
        float s = 0.f;
        for (int k = 0; k < 25; ++k) s += pp[k];
        int rf = 80 >> lo;
        a[jj] = s / (float)(rf * rf);
    }
    float m = fmaxf(fmaxf(a[0], a[1]), fmaxf(a[2], a[3]));
    float e0 = expf(a[0] - m), e1 = expf(a[1] - m), e2 = expf(a[2] - m), e3 = expf(a[3] - m);
    float sum = e0 + e1 + e2 + e3;
    float ev = (j == 0) ? e0 : (j == 1) ? e1 : (j == 2) ? e2 : e3;
    out[t] = ev / sum;
}

extern "C" void kernel_launch(void* const* d_in, const int* in_sizes, int n_in,
                              void* d_out, int out_size, void* d_ws, size_t ws_size,
                              hipStream_t stream) {
    // setup_inputs dict insertion order: f0,w0,b0, f1,w1,b1, f2,w2,b2, f3,w3,b3
    const float* f[4]  = {(const float*)d_in[0], (const float*)d_in[3],
                          (const float*)d_in[6], (const float*)d_in[9]};
    const float* w[4]  = {(const float*)d_in[1], (const float*)d_in[4],
                          (const float*)d_in[7], (const float*)d_in[10]};
    const float* bs[4] = {(const float*)d_in[2], (const float*)d_in[5],
                          (const float*)d_in[8], (const float*)d_in[11]};

    char* ws = (char*)d_ws;
    size_t off = 0;
    short* u1 = (short*)(ws + off); off += (size_t)8 * CCH * 1600 * sizeof(short);
    short* u2 = (short*)(ws + off); off += (size_t)8 * CCH * 400  * sizeof(short);
    short* u3 = (short*)(ws + off); off += (size_t)8 * CCH * 100  * sizeof(short);
    short* wp = (short*)(ws + off); off += (size_t)4 * 65536 * sizeof(short);  // w0..w3 packed
    float* partial = (float*)(ws + off);   // 8*6*25 floats

    static int smax_set = 0;
    if (!smax_set) {
        hipFuncSetAttribute(reinterpret_cast<const void*>(proj0_dots),
                            hipFuncAttributeMaxDynamicSharedMemorySize, 98304);
        smax_set = 1;
    }

    pack_w<<<128, 256, 0, stream>>>(w[0], w[1], w[2], w[3], wp);

    proj_small<<<272, 256, 0, stream>>>(f[1], f[2], f[3], wp,
                                        bs[1], bs[2], bs[3],
                                        u1, u2, u3);

    proj0_dots<<<dim3(25, 8), 512, 98304, stream>>>(f[0], wp, bs[0],
                                                    u1, u2, u3, partial);

    softmax4<<<1, 128, 0, stream>>>(partial, (float*)d_out);
}